// Round 1
// baseline (7524.953 us; speedup 1.0000x reference)
//
#include <hip/hip_runtime.h>
#include <hip/hip_bf16.h>

// SPRGNN: 2-layer GraphConv GNN forward.
// N=100000 nodes, E=1200000 edges, G=1000 graphs.
// Pipeline:
//  h1 = relu(concat(shape_emb[x0], color_emb[x1]) @ W_pre^T + b_pre)   [N,32]
//  agg1 = segment_sum(h1[src], dst)                                    [N,32]
//  h2 = relu(agg1 @ W_rel1^T + b_rel1 + h1 @ W_root1^T)               [N,64]
//  agg2 = segment_sum(h2[src], dst)                                    [N,64]
//  h3 = relu(agg2 @ W_rel2^T + b_rel2 + h2 @ W_root2^T)               [N,64]
//  pooled = segment_mean(h3, batch)                                    [G,64]
//  out = pooled @ W_cls^T + b_cls                                      [G,10]

#define NGRAPHS 1000

// ---------------------------------------------------------------- K1: pre-MLP
__global__ __launch_bounds__(256) void k_pre(
    const int* __restrict__ x,            // [N,2]
    const float* __restrict__ shape_emb,  // [16,8]
    const float* __restrict__ color_emb,  // [8,8]
    const float* __restrict__ W_pre,      // [32,16]
    const float* __restrict__ b_pre,      // [32]
    float* __restrict__ h1, int n)
{
    __shared__ float sW[32 * 16];
    __shared__ float sB[32];
    __shared__ float sSE[16 * 8];
    __shared__ float sCE[8 * 8];
    int t = threadIdx.x;
    for (int i = t; i < 32 * 16; i += 256) sW[i] = W_pre[i];
    if (t < 32) sB[t] = b_pre[t];
    for (int i = t; i < 16 * 8; i += 256) sSE[i] = shape_emb[i];
    if (t < 64) sCE[t] = color_emb[t];
    __syncthreads();

    int i = blockIdx.x * 256 + t;
    if (i >= n) return;
    int s = x[2 * i];
    int c = x[2 * i + 1];
    float in[16];
#pragma unroll
    for (int k = 0; k < 8; ++k) in[k] = sSE[s * 8 + k];
#pragma unroll
    for (int k = 0; k < 8; ++k) in[8 + k] = sCE[c * 8 + k];

    float acc[32];
#pragma unroll
    for (int j = 0; j < 32; ++j) acc[j] = sB[j];
#pragma unroll
    for (int k = 0; k < 16; ++k) {
        float v = in[k];
#pragma unroll
        for (int j = 0; j < 32; ++j) acc[j] += sW[j * 16 + k] * v;
    }
    float4* out = (float4*)(h1 + (size_t)i * 32);
#pragma unroll
    for (int j = 0; j < 8; ++j) {
        out[j] = make_float4(fmaxf(acc[4 * j + 0], 0.f), fmaxf(acc[4 * j + 1], 0.f),
                             fmaxf(acc[4 * j + 2], 0.f), fmaxf(acc[4 * j + 3], 0.f));
    }
}

// ------------------------------------------------- K2/K4: edge scatter (atomic)
// PARTS threads cooperate on one edge; each handles WIDTH/PARTS floats.
template <int WIDTH, int PARTS>
__global__ __launch_bounds__(256) void k_scatter(
    const int* __restrict__ src, const int* __restrict__ dst,
    const float* __restrict__ h, float* __restrict__ agg, int nE)
{
    int tid = blockIdx.x * 256 + threadIdx.x;
    int e = tid / PARTS;
    int p = tid % PARTS;
    if (e >= nE) return;
    int s = src[e];
    int d = dst[e];
    const int CH = WIDTH / PARTS;
    const float* hp = h + (size_t)s * WIDTH + p * CH;
    float* ap = agg + (size_t)d * WIDTH + p * CH;
#pragma unroll
    for (int j = 0; j < CH; j += 4) {
        float4 v = *(const float4*)(hp + j);
        atomicAdd(ap + j + 0, v.x);
        atomicAdd(ap + j + 1, v.y);
        atomicAdd(ap + j + 2, v.z);
        atomicAdd(ap + j + 3, v.w);
    }
}

// ---------------------------------------------------------------- K3: conv1
__global__ __launch_bounds__(256) void k_conv1(
    const float* __restrict__ agg,    // [N,32]
    const float* __restrict__ h,      // [N,32]
    const float* __restrict__ W_rel,  // [64,32]
    const float* __restrict__ b_rel,  // [64]
    const float* __restrict__ W_root, // [64,32]
    float* __restrict__ out, int n)   // [N,64]
{
    __shared__ float sWrel[64 * 32];
    __shared__ float sWroot[64 * 32];
    __shared__ float sB[64];
    int t = threadIdx.x;
    for (int i = t; i < 64 * 32; i += 256) {
        sWrel[i] = W_rel[i];
        sWroot[i] = W_root[i];
    }
    if (t < 64) sB[t] = b_rel[t];
    __syncthreads();

    int i = blockIdx.x * 256 + t;
    if (i >= n) return;

    float a[32], hh[32];
    const float4* ap = (const float4*)(agg + (size_t)i * 32);
    const float4* hp = (const float4*)(h + (size_t)i * 32);
#pragma unroll
    for (int k = 0; k < 8; ++k) {
        float4 v = ap[k];
        a[4 * k] = v.x; a[4 * k + 1] = v.y; a[4 * k + 2] = v.z; a[4 * k + 3] = v.w;
        float4 w = hp[k];
        hh[4 * k] = w.x; hh[4 * k + 1] = w.y; hh[4 * k + 2] = w.z; hh[4 * k + 3] = w.w;
    }
    float acc[64];
#pragma unroll
    for (int j = 0; j < 64; ++j) acc[j] = sB[j];
#pragma unroll 4
    for (int k = 0; k < 32; ++k) {
        float av = a[k], hv = hh[k];
#pragma unroll
        for (int j = 0; j < 64; ++j) acc[j] += sWrel[j * 32 + k] * av + sWroot[j * 32 + k] * hv;
    }
    float4* op = (float4*)(out + (size_t)i * 64);
#pragma unroll
    for (int j = 0; j < 16; ++j) {
        op[j] = make_float4(fmaxf(acc[4 * j + 0], 0.f), fmaxf(acc[4 * j + 1], 0.f),
                            fmaxf(acc[4 * j + 2], 0.f), fmaxf(acc[4 * j + 3], 0.f));
    }
}

// ------------------------------------------------- K5: conv2 + pooled-sum accum
__global__ __launch_bounds__(256) void k_conv2_pool(
    const float* __restrict__ agg,    // [N,64]
    const float* __restrict__ h,      // [N,64]
    const float* __restrict__ W_rel,  // [64,64]
    const float* __restrict__ b_rel,  // [64]
    const float* __restrict__ W_root, // [64,64]
    const int* __restrict__ batch,    // [N]
    float* __restrict__ psum,         // [G,64]
    float* __restrict__ pcnt,         // [G]
    int n)
{
    __shared__ float sWrel[64 * 64];
    __shared__ float sWroot[64 * 64];
    __shared__ float sB[64];
    int t = threadIdx.x;
    for (int i = t; i < 64 * 64; i += 256) {
        sWrel[i] = W_rel[i];
        sWroot[i] = W_root[i];
    }
    if (t < 64) sB[t] = b_rel[t];
    __syncthreads();

    int i = blockIdx.x * 256 + t;
    if (i >= n) return;

    float acc[64];
#pragma unroll
    for (int j = 0; j < 64; ++j) acc[j] = sB[j];

    const float4* ap = (const float4*)(agg + (size_t)i * 64);
    const float4* hp = (const float4*)(h + (size_t)i * 64);
    // k in chunks of 16 to bound register pressure
    for (int kc = 0; kc < 64; kc += 16) {
        float a[16], hh[16];
#pragma unroll
        for (int q = 0; q < 4; ++q) {
            float4 v = ap[kc / 4 + q];
            a[4 * q] = v.x; a[4 * q + 1] = v.y; a[4 * q + 2] = v.z; a[4 * q + 3] = v.w;
            float4 w = hp[kc / 4 + q];
            hh[4 * q] = w.x; hh[4 * q + 1] = w.y; hh[4 * q + 2] = w.z; hh[4 * q + 3] = w.w;
        }
#pragma unroll
        for (int k2 = 0; k2 < 16; ++k2) {
            int k = kc + k2;
            float av = a[k2], hv = hh[k2];
#pragma unroll
            for (int j = 0; j < 64; ++j)
                acc[j] += sWrel[j * 64 + k] * av + sWroot[j * 64 + k] * hv;
        }
    }
    int b = batch[i];
    float* pp = psum + (size_t)b * 64;
#pragma unroll
    for (int j = 0; j < 64; ++j) atomicAdd(pp + j, fmaxf(acc[j], 0.f));
    atomicAdd(pcnt + b, 1.0f);
}

// ---------------------------------------------------------------- K6: classifier
__global__ __launch_bounds__(256) void k_cls(
    const float* __restrict__ psum,  // [G,64]
    const float* __restrict__ pcnt,  // [G]
    const float* __restrict__ W_cls, // [10,64]
    const float* __restrict__ b_cls, // [10]
    float* __restrict__ out, int G)  // [G,10]
{
    __shared__ float sW[10 * 64];
    __shared__ float sB[10];
    int t = threadIdx.x;
    for (int i = t; i < 10 * 64; i += 256) sW[i] = W_cls[i];
    if (t < 10) sB[t] = b_cls[t];
    __syncthreads();

    int g = blockIdx.x * 256 + t;
    if (g >= G) return;
    float inv = 1.0f / fmaxf(pcnt[g], 1.0f);
    float acc[10];
#pragma unroll
    for (int j = 0; j < 10; ++j) acc[j] = sB[j];
    const float4* sp = (const float4*)(psum + (size_t)g * 64);
#pragma unroll
    for (int q = 0; q < 16; ++q) {
        float4 v = sp[q];
        float pv[4] = {v.x * inv, v.y * inv, v.z * inv, v.w * inv};
#pragma unroll
        for (int e = 0; e < 4; ++e) {
            int k = q * 4 + e;
#pragma unroll
            for (int j = 0; j < 10; ++j) acc[j] += sW[j * 64 + k] * pv[e];
        }
    }
#pragma unroll
    for (int j = 0; j < 10; ++j) out[(size_t)g * 10 + j] = acc[j];
}

// ---------------------------------------------------------------- launch
extern "C" void kernel_launch(void* const* d_in, const int* in_sizes, int n_in,
                              void* d_out, int out_size, void* d_ws, size_t ws_size,
                              hipStream_t stream)
{
    const int* x        = (const int*)d_in[0];
    const int* ei       = (const int*)d_in[1];
    const int* batch    = (const int*)d_in[2];
    // d_in[3] = num_graphs (compile-time NGRAPHS)
    const float* shape_emb = (const float*)d_in[4];
    const float* color_emb = (const float*)d_in[5];
    const float* W_pre   = (const float*)d_in[6];
    const float* b_pre   = (const float*)d_in[7];
    const float* W_rel1  = (const float*)d_in[8];
    const float* b_rel1  = (const float*)d_in[9];
    const float* W_root1 = (const float*)d_in[10];
    const float* W_rel2  = (const float*)d_in[11];
    const float* b_rel2  = (const float*)d_in[12];
    const float* W_root2 = (const float*)d_in[13];
    const float* W_cls   = (const float*)d_in[14];
    const float* b_cls   = (const float*)d_in[15];

    const int n  = in_sizes[0] / 2;   // 100000
    const int nE = in_sizes[1] / 2;   // 1200000
    const int G  = NGRAPHS;
    const int* src = ei;
    const int* dst = ei + nE;

    // workspace layout (floats):
    //  [0,        n*32)  h1        -- dead after conv1
    //  [n*32,     n*64)  agg1      -- dead after conv1
    //  [n*64,     n*128) h2
    //  [0,        n*64)  agg2      -- reuses h1+agg1 region
    //  [n*128, n*128+G*64) psum
    //  [n*128+G*64, +G)    pcnt
    float* ws   = (float*)d_ws;
    float* h1   = ws;
    float* agg1 = ws + (size_t)n * 32;
    float* h2   = ws + (size_t)n * 64;
    float* agg2 = ws;  // overlap: safe, h1/agg1 dead before it's written
    float* psum = ws + (size_t)n * 128;
    float* pcnt = psum + (size_t)G * 64;

    hipMemsetAsync(agg1, 0, (size_t)n * 32 * sizeof(float), stream);
    k_pre<<<(n + 255) / 256, 256, 0, stream>>>(x, shape_emb, color_emb, W_pre, b_pre, h1, n);
    k_scatter<32, 2><<<((size_t)nE * 2 + 255) / 256, 256, 0, stream>>>(src, dst, h1, agg1, nE);
    k_conv1<<<(n + 255) / 256, 256, 0, stream>>>(agg1, h1, W_rel1, b_rel1, W_root1, h2, n);
    hipMemsetAsync(agg2, 0, (size_t)n * 64 * sizeof(float), stream);
    hipMemsetAsync(psum, 0, (size_t)(G * 64 + G) * sizeof(float), stream);
    k_scatter<64, 4><<<((size_t)nE * 4 + 255) / 256, 256, 0, stream>>>(src, dst, h2, agg2, nE);
    k_conv2_pool<<<(n + 255) / 256, 256, 0, stream>>>(agg2, h2, W_rel2, b_rel2, W_root2, batch,
                                                      psum, pcnt, n);
    k_cls<<<(G + 255) / 256, 256, 0, stream>>>(psum, pcnt, W_cls, b_cls, (float*)d_out, G);
}

// Round 2
// 1222.090 us; speedup vs baseline: 6.1574x; 6.1574x over previous
//
#include <hip/hip_runtime.h>
#include <hip/hip_bf16.h>

// SPRGNN: 2-layer GraphConv GNN forward. CSR-gather formulation (no f32 atomics).
// N=100000 nodes, E=1200000 edges, G=1000 graphs.
//
// Per call:
//  CSR build: hist(dst) -> scan -> scatter edge srcs into dst-sorted order
//  h1 = relu(embed @ W_pre^T + b_pre)                  [N,32]
//  agg1 = gather-sum via CSR                           [N,32]
//  h2 = relu(agg1 @ W_rel1^T + b_rel1 + h1 @ W_root1^T)[N,64]
//  agg2 = gather-sum via CSR                           [N,64]
//  h3 = relu(agg2 @ W_rel2^T + b_rel2 + h2 @ W_root2^T)[N,64]  (in-place over agg2)
//  out[g] = mean_{batch==g}(h3) @ W_cls^T + b_cls      [G,10]  (block-per-graph, batch sorted)

#define NGRAPHS 1000

// ---------------------------------------------------------------- CSR build
__global__ __launch_bounds__(256) void k_hist(const int* __restrict__ dst,
                                              int* __restrict__ hist, int nE)
{
    int e = blockIdx.x * 256 + threadIdx.x;
    if (e < nE) atomicAdd(&hist[dst[e]], 1);
}

// single-block exclusive scan of hist[0..n) -> row_ptr[0..n], cursor copy
__global__ __launch_bounds__(1024) void k_scan(const int* __restrict__ hist,
                                               int* __restrict__ row_ptr,
                                               int* __restrict__ cursor, int n)
{
    __shared__ int s[1024];
    int t = threadIdx.x;
    int C = (n + 1023) / 1024;
    int beg = t * C;
    int end = min(beg + C, n);
    int sum = 0;
    for (int i = beg; i < end; ++i) sum += hist[i];
    s[t] = sum;
    __syncthreads();
    for (int off = 1; off < 1024; off <<= 1) {
        int v = (t >= off) ? s[t - off] : 0;
        __syncthreads();
        s[t] += v;
        __syncthreads();
    }
    int base = (t == 0) ? 0 : s[t - 1];
    for (int i = beg; i < end; ++i) {
        row_ptr[i] = base;
        cursor[i] = base;
        base += hist[i];
    }
    if (t == 0) row_ptr[n] = s[1023];
}

__global__ __launch_bounds__(256) void k_scatteridx(
    const int* __restrict__ src, const int* __restrict__ dst,
    int* __restrict__ cursor, int* __restrict__ sorted_src, int nE)
{
    int e = blockIdx.x * 256 + threadIdx.x;
    if (e >= nE) return;
    int pos = atomicAdd(&cursor[dst[e]], 1);
    sorted_src[pos] = src[e];
}

// ---------------------------------------------------------------- K1: pre-MLP
__global__ __launch_bounds__(256) void k_pre(
    const int* __restrict__ x,
    const float* __restrict__ shape_emb, const float* __restrict__ color_emb,
    const float* __restrict__ W_pre, const float* __restrict__ b_pre,
    float* __restrict__ h1, int n)
{
    __shared__ float sW[32 * 16];
    __shared__ float sB[32];
    __shared__ float sSE[16 * 8];
    __shared__ float sCE[8 * 8];
    int t = threadIdx.x;
    for (int i = t; i < 32 * 16; i += 256) sW[i] = W_pre[i];
    if (t < 32) sB[t] = b_pre[t];
    for (int i = t; i < 16 * 8; i += 256) sSE[i] = shape_emb[i];
    if (t < 64) sCE[t] = color_emb[t];
    __syncthreads();

    int i = blockIdx.x * 256 + t;
    if (i >= n) return;
    int s = x[2 * i];
    int c = x[2 * i + 1];
    float in[16];
#pragma unroll
    for (int k = 0; k < 8; ++k) in[k] = sSE[s * 8 + k];
#pragma unroll
    for (int k = 0; k < 8; ++k) in[8 + k] = sCE[c * 8 + k];

    float acc[32];
#pragma unroll
    for (int j = 0; j < 32; ++j) acc[j] = sB[j];
#pragma unroll
    for (int k = 0; k < 16; ++k) {
        float v = in[k];
#pragma unroll
        for (int j = 0; j < 32; ++j) acc[j] += sW[j * 16 + k] * v;
    }
    float4* out = (float4*)(h1 + (size_t)i * 32);
#pragma unroll
    for (int j = 0; j < 8; ++j)
        out[j] = make_float4(fmaxf(acc[4 * j + 0], 0.f), fmaxf(acc[4 * j + 1], 0.f),
                             fmaxf(acc[4 * j + 2], 0.f), fmaxf(acc[4 * j + 3], 0.f));
}

// ------------------------------------------------- gather aggregation via CSR
// PARTS threads per node; each owns CH=WIDTH/PARTS=8 floats (2x float4).
template <int WIDTH, int PARTS>
__global__ __launch_bounds__(256) void k_agg(
    const int* __restrict__ row_ptr, const int* __restrict__ sorted_src,
    const float* __restrict__ h, float* __restrict__ agg, int n)
{
    int tid = blockIdx.x * 256 + threadIdx.x;
    int i = tid / PARTS;
    int p = tid % PARTS;
    if (i >= n) return;
    const int CH = WIDTH / PARTS;  // 8
    float4 a0 = make_float4(0.f, 0.f, 0.f, 0.f);
    float4 a1 = make_float4(0.f, 0.f, 0.f, 0.f);
    int e0 = row_ptr[i], e1 = row_ptr[i + 1];
    const float* hp = h + p * CH;
    for (int e = e0; e < e1; ++e) {
        int s = sorted_src[e];
        const float4* r = (const float4*)(hp + (size_t)s * WIDTH);
        float4 v0 = r[0], v1 = r[1];
        a0.x += v0.x; a0.y += v0.y; a0.z += v0.z; a0.w += v0.w;
        a1.x += v1.x; a1.y += v1.y; a1.z += v1.z; a1.w += v1.w;
    }
    float4* ap = (float4*)(agg + (size_t)i * WIDTH + p * CH);
    ap[0] = a0;
    ap[1] = a1;
}

// ---------------------------------------------------------------- K3: conv1
__global__ __launch_bounds__(256) void k_conv1(
    const float* __restrict__ agg, const float* __restrict__ h,
    const float* __restrict__ W_rel, const float* __restrict__ b_rel,
    const float* __restrict__ W_root,
    float* __restrict__ out, int n)
{
    __shared__ float sWrel[64 * 32];
    __shared__ float sWroot[64 * 32];
    __shared__ float sB[64];
    int t = threadIdx.x;
    for (int i = t; i < 64 * 32; i += 256) {
        sWrel[i] = W_rel[i];
        sWroot[i] = W_root[i];
    }
    if (t < 64) sB[t] = b_rel[t];
    __syncthreads();

    int i = blockIdx.x * 256 + t;
    if (i >= n) return;

    float a[32], hh[32];
    const float4* ap = (const float4*)(agg + (size_t)i * 32);
    const float4* hp = (const float4*)(h + (size_t)i * 32);
#pragma unroll
    for (int k = 0; k < 8; ++k) {
        float4 v = ap[k];
        a[4 * k] = v.x; a[4 * k + 1] = v.y; a[4 * k + 2] = v.z; a[4 * k + 3] = v.w;
        float4 w = hp[k];
        hh[4 * k] = w.x; hh[4 * k + 1] = w.y; hh[4 * k + 2] = w.z; hh[4 * k + 3] = w.w;
    }
    float acc[64];
#pragma unroll
    for (int j = 0; j < 64; ++j) acc[j] = sB[j];
#pragma unroll 4
    for (int k = 0; k < 32; ++k) {
        float av = a[k], hv = hh[k];
#pragma unroll
        for (int j = 0; j < 64; ++j) acc[j] += sWrel[j * 32 + k] * av + sWroot[j * 32 + k] * hv;
    }
    float4* op = (float4*)(out + (size_t)i * 64);
#pragma unroll
    for (int j = 0; j < 16; ++j)
        op[j] = make_float4(fmaxf(acc[4 * j + 0], 0.f), fmaxf(acc[4 * j + 1], 0.f),
                            fmaxf(acc[4 * j + 2], 0.f), fmaxf(acc[4 * j + 3], 0.f));
}

// ---------------------------------------------------------------- K5: conv2 (h3 in-place over agg)
__global__ __launch_bounds__(256) void k_conv2(
    float* __restrict__ agg,            // [N,64] in: agg2, out: h3 (in-place, own row only)
    const float* __restrict__ h,        // [N,64]
    const float* __restrict__ W_rel, const float* __restrict__ b_rel,
    const float* __restrict__ W_root, int n)
{
    __shared__ float sWrel[64 * 64];
    __shared__ float sWroot[64 * 64];
    __shared__ float sB[64];
    int t = threadIdx.x;
    for (int i = t; i < 64 * 64; i += 256) {
        sWrel[i] = W_rel[i];
        sWroot[i] = W_root[i];
    }
    if (t < 64) sB[t] = b_rel[t];
    __syncthreads();

    int i = blockIdx.x * 256 + t;
    if (i >= n) return;

    float acc[64];
#pragma unroll
    for (int j = 0; j < 64; ++j) acc[j] = sB[j];

    const float4* ap = (const float4*)(agg + (size_t)i * 64);
    const float4* hp = (const float4*)(h + (size_t)i * 64);
    for (int kc = 0; kc < 64; kc += 16) {
        float a[16], hh[16];
#pragma unroll
        for (int q = 0; q < 4; ++q) {
            float4 v = ap[kc / 4 + q];
            a[4 * q] = v.x; a[4 * q + 1] = v.y; a[4 * q + 2] = v.z; a[4 * q + 3] = v.w;
            float4 w = hp[kc / 4 + q];
            hh[4 * q] = w.x; hh[4 * q + 1] = w.y; hh[4 * q + 2] = w.z; hh[4 * q + 3] = w.w;
        }
#pragma unroll
        for (int k2 = 0; k2 < 16; ++k2) {
            int k = kc + k2;
            float av = a[k2], hv = hh[k2];
#pragma unroll
            for (int j = 0; j < 64; ++j)
                acc[j] += sWrel[j * 64 + k] * av + sWroot[j * 64 + k] * hv;
        }
    }
    float4* op = (float4*)(agg + (size_t)i * 64);
#pragma unroll
    for (int j = 0; j < 16; ++j)
        op[j] = make_float4(fmaxf(acc[4 * j + 0], 0.f), fmaxf(acc[4 * j + 1], 0.f),
                            fmaxf(acc[4 * j + 2], 0.f), fmaxf(acc[4 * j + 3], 0.f));
}

// ------------------------------------------- pool (block per graph) + classifier
__global__ __launch_bounds__(256) void k_pool_cls(
    const float* __restrict__ h3,     // [N,64]
    const int* __restrict__ batch,    // [N] sorted
    const float* __restrict__ W_cls,  // [10,64]
    const float* __restrict__ b_cls,  // [10]
    float* __restrict__ out, int n)   // [G,10]
{
    __shared__ float part[4][64];
    __shared__ float pool[64];
    __shared__ int range[2];
    int g = blockIdx.x;
    int t = threadIdx.x;

    if (t < 2) {
        // lower_bound(batch, g + t): first idx with batch[idx] >= g+t
        int key = g + t;
        int lo = 0, hi = n;
        while (lo < hi) {
            int mid = (lo + hi) >> 1;
            if (batch[mid] < key) lo = mid + 1; else hi = mid;
        }
        range[t] = lo;
    }
    __syncthreads();
    int start = range[0], end = range[1];

    int j = t & 63;
    int sub = t >> 6;  // 0..3
    float local = 0.f;
    for (int i = start + sub; i < end; i += 4) local += h3[(size_t)i * 64 + j];
    part[sub][j] = local;
    __syncthreads();

    if (t < 64) {
        float cnt = (float)(end - start);
        float inv = 1.0f / fmaxf(cnt, 1.0f);
        pool[t] = (part[0][t] + part[1][t] + part[2][t] + part[3][t]) * inv;
    }
    __syncthreads();

    if (t < 10) {
        float acc = b_cls[t];
#pragma unroll
        for (int k = 0; k < 64; ++k) acc += W_cls[t * 64 + k] * pool[k];
        out[(size_t)g * 10 + t] = acc;
    }
}

// ---------------------------------------------------------------- launch
extern "C" void kernel_launch(void* const* d_in, const int* in_sizes, int n_in,
                              void* d_out, int out_size, void* d_ws, size_t ws_size,
                              hipStream_t stream)
{
    const int* x        = (const int*)d_in[0];
    const int* ei       = (const int*)d_in[1];
    const int* batch    = (const int*)d_in[2];
    const float* shape_emb = (const float*)d_in[4];
    const float* color_emb = (const float*)d_in[5];
    const float* W_pre   = (const float*)d_in[6];
    const float* b_pre   = (const float*)d_in[7];
    const float* W_rel1  = (const float*)d_in[8];
    const float* b_rel1  = (const float*)d_in[9];
    const float* W_root1 = (const float*)d_in[10];
    const float* W_rel2  = (const float*)d_in[11];
    const float* b_rel2  = (const float*)d_in[12];
    const float* W_root2 = (const float*)d_in[13];
    const float* W_cls   = (const float*)d_in[14];
    const float* b_cls   = (const float*)d_in[15];

    const int n  = in_sizes[0] / 2;   // 100000
    const int nE = in_sizes[1] / 2;   // 1200000
    const int G  = NGRAPHS;
    const int* src = ei;
    const int* dst = ei + nE;

    // workspace layout:
    //  floats: [0,n*32) h1 | [n*32,n*64) agg1 | [n*64,n*128) h2
    //          agg2/h3 = [0,n*64) (reuses h1+agg1, dead after conv1)
    //  ints  at float-offset n*128: row_ptr[n+1] | cursor[n] | sorted_src[E]
    //          hist aliases cursor (hist consumed by scan before cursor written)
    float* ws   = (float*)d_ws;
    float* h1   = ws;
    float* agg1 = ws + (size_t)n * 32;
    float* h2   = ws + (size_t)n * 64;
    float* agg2 = ws;  // also h3 (in-place)
    int* ints      = (int*)(ws + (size_t)n * 128);
    int* row_ptr   = ints;                 // n+1
    int* hist      = ints + (n + 1);       // n   (separate from cursor!)
    int* cursor    = ints + (n + 1) + n;   // n
    int* sorted_src= ints + (n + 1) + 2 * n; // E

    const int EB = (nE + 255) / 256;
    const int NB = (n + 255) / 256;

    // --- CSR build ---
    hipMemsetAsync(hist, 0, (size_t)n * sizeof(int), stream);
    k_hist<<<EB, 256, 0, stream>>>(dst, hist, nE);
    k_scan<<<1, 1024, 0, stream>>>(hist, row_ptr, cursor, n);
    k_scatteridx<<<EB, 256, 0, stream>>>(src, dst, cursor, sorted_src, nE);

    // --- forward ---
    k_pre<<<NB, 256, 0, stream>>>(x, shape_emb, color_emb, W_pre, b_pre, h1, n);
    k_agg<32, 4><<<((size_t)n * 4 + 255) / 256, 256, 0, stream>>>(row_ptr, sorted_src, h1, agg1, n);
    k_conv1<<<NB, 256, 0, stream>>>(agg1, h1, W_rel1, b_rel1, W_root1, h2, n);
    k_agg<64, 8><<<((size_t)n * 8 + 255) / 256, 256, 0, stream>>>(row_ptr, sorted_src, h2, agg2, n);
    k_conv2<<<NB, 256, 0, stream>>>(agg2, h2, W_rel2, b_rel2, W_root2, n);
    k_pool_cls<<<G, 256, 0, stream>>>(agg2, batch, W_cls, b_cls, (float*)d_out, n);
}

// Round 3
// 743.100 us; speedup vs baseline: 10.1264x; 1.6446x over previous
//
#include <hip/hip_runtime.h>
#include <hip/hip_bf16.h>

// SPRGNN: 2-layer GraphConv GNN forward. CSR-gather formulation (no f32 atomics).
// N=100000 nodes, E=1200000 edges, G=1000 graphs.
//
// R3: conv kernels restructured to avoid register spills (R2: k_conv1 had
// VGPR=256 + 1.3GB scratch traffic). Block = 4 waves x 64 nodes; each wave
// owns a 16-channel output quarter -> acc[16]/thread, wave-uniform LDS
// weight reads (broadcast, conflict-free).

#define NGRAPHS 1000

// ---------------------------------------------------------------- CSR build
__global__ __launch_bounds__(256) void k_hist(const int* __restrict__ dst,
                                              int* __restrict__ hist, int nE)
{
    int e = blockIdx.x * 256 + threadIdx.x;
    if (e < nE) atomicAdd(&hist[dst[e]], 1);
}

// single-block exclusive scan of hist[0..n) -> row_ptr[0..n], cursor copy
__global__ __launch_bounds__(1024) void k_scan(const int* __restrict__ hist,
                                               int* __restrict__ row_ptr,
                                               int* __restrict__ cursor, int n)
{
    __shared__ int s[1024];
    int t = threadIdx.x;
    int C = (n + 1023) / 1024;
    int beg = t * C;
    int end = min(beg + C, n);
    int sum = 0;
    for (int i = beg; i < end; ++i) sum += hist[i];
    s[t] = sum;
    __syncthreads();
    for (int off = 1; off < 1024; off <<= 1) {
        int v = (t >= off) ? s[t - off] : 0;
        __syncthreads();
        s[t] += v;
        __syncthreads();
    }
    int base = (t == 0) ? 0 : s[t - 1];
    for (int i = beg; i < end; ++i) {
        row_ptr[i] = base;
        cursor[i] = base;
        base += hist[i];
    }
    if (t == 0) row_ptr[n] = s[1023];
}

__global__ __launch_bounds__(256) void k_scatteridx(
    const int* __restrict__ src, const int* __restrict__ dst,
    int* __restrict__ cursor, int* __restrict__ sorted_src, int nE)
{
    int e = blockIdx.x * 256 + threadIdx.x;
    if (e >= nE) return;
    int pos = atomicAdd(&cursor[dst[e]], 1);
    sorted_src[pos] = src[e];
}

// ---------------------------------------------------------------- K1: pre-MLP
__global__ __launch_bounds__(256) void k_pre(
    const int* __restrict__ x,
    const float* __restrict__ shape_emb, const float* __restrict__ color_emb,
    const float* __restrict__ W_pre, const float* __restrict__ b_pre,
    float* __restrict__ h1, int n)
{
    __shared__ float sW[32 * 16];
    __shared__ float sB[32];
    __shared__ float sSE[16 * 8];
    __shared__ float sCE[8 * 8];
    int t = threadIdx.x;
    for (int i = t; i < 32 * 16; i += 256) sW[i] = W_pre[i];
    if (t < 32) sB[t] = b_pre[t];
    for (int i = t; i < 16 * 8; i += 256) sSE[i] = shape_emb[i];
    if (t < 64) sCE[t] = color_emb[t];
    __syncthreads();

    int i = blockIdx.x * 256 + t;
    if (i >= n) return;
    int s = x[2 * i];
    int c = x[2 * i + 1];
    float in[16];
#pragma unroll
    for (int k = 0; k < 8; ++k) in[k] = sSE[s * 8 + k];
#pragma unroll
    for (int k = 0; k < 8; ++k) in[8 + k] = sCE[c * 8 + k];

    float acc[32];
#pragma unroll
    for (int j = 0; j < 32; ++j) acc[j] = sB[j];
#pragma unroll
    for (int k = 0; k < 16; ++k) {
        float v = in[k];
#pragma unroll
        for (int j = 0; j < 32; ++j) acc[j] += sW[j * 16 + k] * v;
    }
    float4* out = (float4*)(h1 + (size_t)i * 32);
#pragma unroll
    for (int j = 0; j < 8; ++j)
        out[j] = make_float4(fmaxf(acc[4 * j + 0], 0.f), fmaxf(acc[4 * j + 1], 0.f),
                             fmaxf(acc[4 * j + 2], 0.f), fmaxf(acc[4 * j + 3], 0.f));
}

// ------------------------------------------------- gather aggregation via CSR
// PARTS threads per node; each owns 8 floats (2x float4). Edge loop unrolled x2
// to keep two gather loads in flight (latency-bound, avg deg ~12).
template <int WIDTH, int PARTS>
__global__ __launch_bounds__(256) void k_agg(
    const int* __restrict__ row_ptr, const int* __restrict__ sorted_src,
    const float* __restrict__ h, float* __restrict__ agg, int n)
{
    int tid = blockIdx.x * 256 + threadIdx.x;
    int i = tid / PARTS;
    int p = tid % PARTS;
    if (i >= n) return;
    float4 a0 = make_float4(0.f, 0.f, 0.f, 0.f);
    float4 a1 = make_float4(0.f, 0.f, 0.f, 0.f);
    float4 b0 = make_float4(0.f, 0.f, 0.f, 0.f);
    float4 b1 = make_float4(0.f, 0.f, 0.f, 0.f);
    int e0 = row_ptr[i], e1 = row_ptr[i + 1];
    const float* hp = h + p * 8;
    int e = e0;
    for (; e + 2 <= e1; e += 2) {
        int s0 = sorted_src[e];
        int s1 = sorted_src[e + 1];
        const float4* r0 = (const float4*)(hp + (size_t)s0 * WIDTH);
        const float4* r1 = (const float4*)(hp + (size_t)s1 * WIDTH);
        float4 v00 = r0[0], v01 = r0[1];
        float4 v10 = r1[0], v11 = r1[1];
        a0.x += v00.x; a0.y += v00.y; a0.z += v00.z; a0.w += v00.w;
        a1.x += v01.x; a1.y += v01.y; a1.z += v01.z; a1.w += v01.w;
        b0.x += v10.x; b0.y += v10.y; b0.z += v10.z; b0.w += v10.w;
        b1.x += v11.x; b1.y += v11.y; b1.z += v11.z; b1.w += v11.w;
    }
    if (e < e1) {
        int s0 = sorted_src[e];
        const float4* r0 = (const float4*)(hp + (size_t)s0 * WIDTH);
        float4 v00 = r0[0], v01 = r0[1];
        a0.x += v00.x; a0.y += v00.y; a0.z += v00.z; a0.w += v00.w;
        a1.x += v01.x; a1.y += v01.y; a1.z += v01.z; a1.w += v01.w;
    }
    a0.x += b0.x; a0.y += b0.y; a0.z += b0.z; a0.w += b0.w;
    a1.x += b1.x; a1.y += b1.y; a1.z += b1.z; a1.w += b1.w;
    float4* ap = (float4*)(agg + (size_t)i * WIDTH + p * 8);
    ap[0] = a0;
    ap[1] = a1;
}

// ---------------------------------------------------- conv (spill-free layout)
// Block = 256 threads = 4 waves, 64 nodes (lane = node). Wave w computes
// output channels [w*16, w*16+16). LDS weight index is wave-uniform ->
// broadcast read, no bank conflicts. acc[16]/thread -> no spills.
// Safe when out aliases agg (conv2 in-place): __syncthreads before store.
template <int WIN>
__global__ __launch_bounds__(256) void k_conv(
    const float* __restrict__ agg, const float* __restrict__ h,
    const float* __restrict__ W_rel, const float* __restrict__ b_rel,
    const float* __restrict__ W_root, float* __restrict__ out, int n)
{
    __shared__ float sWrel[64 * WIN];
    __shared__ float sWroot[64 * WIN];
    __shared__ float sB[64];
    int t = threadIdx.x;
    for (int i = t; i < 64 * WIN; i += 256) {
        sWrel[i] = W_rel[i];
        sWroot[i] = W_root[i];
    }
    if (t < 64) sB[t] = b_rel[t];
    __syncthreads();

    int lane = t & 63;
    int wq = t >> 6;                       // output quarter
    int i = blockIdx.x * 64 + lane;
    bool active = (i < n);

    float acc[16];
#pragma unroll
    for (int j = 0; j < 16; ++j) acc[j] = sB[wq * 16 + j];
    const float* wr = sWrel + (size_t)(wq * 16) * WIN;
    const float* wo = sWroot + (size_t)(wq * 16) * WIN;

    if (active) {
        const float4* ap = (const float4*)(agg + (size_t)i * WIN);
        const float4* hp = (const float4*)(h + (size_t)i * WIN);
#pragma unroll
        for (int kc = 0; kc < WIN / 4; ++kc) {
            float4 a4 = ap[kc];
            float4 h4 = hp[kc];
            float av[4] = {a4.x, a4.y, a4.z, a4.w};
            float hv[4] = {h4.x, h4.y, h4.z, h4.w};
#pragma unroll
            for (int q = 0; q < 4; ++q) {
                int k = kc * 4 + q;
#pragma unroll
                for (int j = 0; j < 16; ++j)
                    acc[j] += wr[j * WIN + k] * av[q] + wo[j * WIN + k] * hv[q];
            }
        }
    }
    __syncthreads();  // all reads done before any in-place store
    if (active) {
        float4* op = (float4*)(out + (size_t)i * 64 + wq * 16);
#pragma unroll
        for (int j = 0; j < 4; ++j)
            op[j] = make_float4(fmaxf(acc[4 * j + 0], 0.f), fmaxf(acc[4 * j + 1], 0.f),
                                fmaxf(acc[4 * j + 2], 0.f), fmaxf(acc[4 * j + 3], 0.f));
    }
}

// ------------------------------------------- pool (block per graph) + classifier
__global__ __launch_bounds__(256) void k_pool_cls(
    const float* __restrict__ h3,     // [N,64]
    const int* __restrict__ batch,    // [N] sorted
    const float* __restrict__ W_cls,  // [10,64]
    const float* __restrict__ b_cls,  // [10]
    float* __restrict__ out, int n)   // [G,10]
{
    __shared__ float part[4][64];
    __shared__ float pool[64];
    __shared__ int range[2];
    int g = blockIdx.x;
    int t = threadIdx.x;

    if (t < 2) {
        int key = g + t;
        int lo = 0, hi = n;
        while (lo < hi) {
            int mid = (lo + hi) >> 1;
            if (batch[mid] < key) lo = mid + 1; else hi = mid;
        }
        range[t] = lo;
    }
    __syncthreads();
    int start = range[0], end = range[1];

    int j = t & 63;
    int sub = t >> 6;  // 0..3
    float local = 0.f;
    for (int i = start + sub; i < end; i += 4) local += h3[(size_t)i * 64 + j];
    part[sub][j] = local;
    __syncthreads();

    if (t < 64) {
        float cnt = (float)(end - start);
        float inv = 1.0f / fmaxf(cnt, 1.0f);
        pool[t] = (part[0][t] + part[1][t] + part[2][t] + part[3][t]) * inv;
    }
    __syncthreads();

    if (t < 10) {
        float acc = b_cls[t];
#pragma unroll
        for (int k = 0; k < 64; ++k) acc += W_cls[t * 64 + k] * pool[k];
        out[(size_t)g * 10 + t] = acc;
    }
}

// ---------------------------------------------------------------- launch
extern "C" void kernel_launch(void* const* d_in, const int* in_sizes, int n_in,
                              void* d_out, int out_size, void* d_ws, size_t ws_size,
                              hipStream_t stream)
{
    const int* x        = (const int*)d_in[0];
    const int* ei       = (const int*)d_in[1];
    const int* batch    = (const int*)d_in[2];
    const float* shape_emb = (const float*)d_in[4];
    const float* color_emb = (const float*)d_in[5];
    const float* W_pre   = (const float*)d_in[6];
    const float* b_pre   = (const float*)d_in[7];
    const float* W_rel1  = (const float*)d_in[8];
    const float* b_rel1  = (const float*)d_in[9];
    const float* W_root1 = (const float*)d_in[10];
    const float* W_rel2  = (const float*)d_in[11];
    const float* b_rel2  = (const float*)d_in[12];
    const float* W_root2 = (const float*)d_in[13];
    const float* W_cls   = (const float*)d_in[14];
    const float* b_cls   = (const float*)d_in[15];

    const int n  = in_sizes[0] / 2;   // 100000
    const int nE = in_sizes[1] / 2;   // 1200000
    const int G  = NGRAPHS;
    const int* src = ei;
    const int* dst = ei + nE;

    // workspace layout:
    //  floats: [0,n*32) h1 | [n*32,n*64) agg1 | [n*64,n*128) h2
    //          agg2/h3 = [0,n*64) (reuses h1+agg1, dead after conv1)
    //  ints  at float-offset n*128: row_ptr[n+1] | hist[n] | cursor[n] | sorted_src[E]
    float* ws   = (float*)d_ws;
    float* h1   = ws;
    float* agg1 = ws + (size_t)n * 32;
    float* h2   = ws + (size_t)n * 64;
    float* agg2 = ws;  // also h3 (conv2 writes in-place)
    int* ints       = (int*)(ws + (size_t)n * 128);
    int* row_ptr    = ints;                    // n+1
    int* hist       = ints + (n + 1);          // n
    int* cursor     = ints + (n + 1) + n;      // n
    int* sorted_src = ints + (n + 1) + 2 * n;  // E

    const int EB = (nE + 255) / 256;
    const int NB = (n + 255) / 256;
    const int CB = (n + 63) / 64;

    // --- CSR build ---
    hipMemsetAsync(hist, 0, (size_t)n * sizeof(int), stream);
    k_hist<<<EB, 256, 0, stream>>>(dst, hist, nE);
    k_scan<<<1, 1024, 0, stream>>>(hist, row_ptr, cursor, n);
    k_scatteridx<<<EB, 256, 0, stream>>>(src, dst, cursor, sorted_src, nE);

    // --- forward ---
    k_pre<<<NB, 256, 0, stream>>>(x, shape_emb, color_emb, W_pre, b_pre, h1, n);
    k_agg<32, 4><<<((size_t)n * 4 + 255) / 256, 256, 0, stream>>>(row_ptr, sorted_src, h1, agg1, n);
    k_conv<32><<<CB, 256, 0, stream>>>(agg1, h1, W_rel1, b_rel1, W_root1, h2, n);
    k_agg<64, 8><<<((size_t)n * 8 + 255) / 256, 256, 0, stream>>>(row_ptr, sorted_src, h2, agg2, n);
    k_conv<64><<<CB, 256, 0, stream>>>(agg2, h2, W_rel2, b_rel2, W_root2, agg2, n);
    k_pool_cls<<<G, 256, 0, stream>>>(agg2, batch, W_cls, b_cls, (float*)d_out, n);
}

// Round 4
// 528.900 us; speedup vs baseline: 14.2276x; 1.4050x over previous
//
#include <hip/hip_runtime.h>
#include <hip/hip_bf16.h>

// SPRGNN: 2-layer GraphConv GNN forward. CSR-gather formulation (no f32 atomics).
// N=100000 nodes, E=1200000 edges, G=1000 graphs.
//
// R4: single-block k_scan (235us, one CU, latency-bound) replaced with a
// 3-phase multi-block scan (~15us). Everything else as R3.

#define NGRAPHS 1000
#define SCAN_CHUNK 4096   // elements per block; 16 per thread

// ---------------------------------------------------------------- CSR build
__global__ __launch_bounds__(256) void k_hist(const int* __restrict__ dst,
                                              int* __restrict__ hist, int nE)
{
    int e = blockIdx.x * 256 + threadIdx.x;
    if (e < nE) atomicAdd(&hist[dst[e]], 1);
}

// phase 1: per-block sum of hist chunk
__global__ __launch_bounds__(256) void k_scan_part(const int* __restrict__ hist,
                                                   int* __restrict__ bsum, int n)
{
    __shared__ int s[256];
    int t = threadIdx.x;
    int beg = blockIdx.x * SCAN_CHUNK + t * 16;
    int sum = 0;
#pragma unroll
    for (int q = 0; q < 16; ++q) {
        int i = beg + q;
        if (i < n) sum += hist[i];
    }
    s[t] = sum;
    __syncthreads();
    for (int off = 128; off > 0; off >>= 1) {
        if (t < off) s[t] += s[t + off];
        __syncthreads();
    }
    if (t == 0) bsum[blockIdx.x] = s[0];
}

// phase 2: exclusive scan of B block sums (B small, serial) + total -> row_ptr[n]
__global__ __launch_bounds__(64) void k_scan_mid(const int* __restrict__ bsum,
                                                 int* __restrict__ boffs,
                                                 int* __restrict__ row_ptr,
                                                 int B, int n)
{
    if (threadIdx.x == 0) {
        int run = 0;
        for (int b = 0; b < B; ++b) {
            boffs[b] = run;
            run += bsum[b];
        }
        row_ptr[n] = run;
    }
}

// phase 3: block-local exclusive scan + block offset -> row_ptr, cursor
__global__ __launch_bounds__(256) void k_scan_apply(const int* __restrict__ hist,
                                                    const int* __restrict__ boffs,
                                                    int* __restrict__ row_ptr,
                                                    int* __restrict__ cursor, int n)
{
    __shared__ int s[256];
    int t = threadIdx.x;
    int beg = blockIdx.x * SCAN_CHUNK + t * 16;
    int v[16];
    int sum = 0;
#pragma unroll
    for (int q = 0; q < 16; ++q) {
        int i = beg + q;
        v[q] = (i < n) ? hist[i] : 0;
        sum += v[q];
    }
    s[t] = sum;
    __syncthreads();
    // Hillis-Steele inclusive scan over 256 thread partials
    for (int off = 1; off < 256; off <<= 1) {
        int x = (t >= off) ? s[t - off] : 0;
        __syncthreads();
        s[t] += x;
        __syncthreads();
    }
    int base = boffs[blockIdx.x] + ((t == 0) ? 0 : s[t - 1]);
#pragma unroll
    for (int q = 0; q < 16; ++q) {
        int i = beg + q;
        if (i < n) {
            row_ptr[i] = base;
            cursor[i] = base;
            base += v[q];
        }
    }
}

__global__ __launch_bounds__(256) void k_scatteridx(
    const int* __restrict__ src, const int* __restrict__ dst,
    int* __restrict__ cursor, int* __restrict__ sorted_src, int nE)
{
    int e = blockIdx.x * 256 + threadIdx.x;
    if (e >= nE) return;
    int pos = atomicAdd(&cursor[dst[e]], 1);
    sorted_src[pos] = src[e];
}

// ---------------------------------------------------------------- K1: pre-MLP
__global__ __launch_bounds__(256) void k_pre(
    const int* __restrict__ x,
    const float* __restrict__ shape_emb, const float* __restrict__ color_emb,
    const float* __restrict__ W_pre, const float* __restrict__ b_pre,
    float* __restrict__ h1, int n)
{
    __shared__ float sW[32 * 16];
    __shared__ float sB[32];
    __shared__ float sSE[16 * 8];
    __shared__ float sCE[8 * 8];
    int t = threadIdx.x;
    for (int i = t; i < 32 * 16; i += 256) sW[i] = W_pre[i];
    if (t < 32) sB[t] = b_pre[t];
    for (int i = t; i < 16 * 8; i += 256) sSE[i] = shape_emb[i];
    if (t < 64) sCE[t] = color_emb[t];
    __syncthreads();

    int i = blockIdx.x * 256 + t;
    if (i >= n) return;
    int s = x[2 * i];
    int c = x[2 * i + 1];
    float in[16];
#pragma unroll
    for (int k = 0; k < 8; ++k) in[k] = sSE[s * 8 + k];
#pragma unroll
    for (int k = 0; k < 8; ++k) in[8 + k] = sCE[c * 8 + k];

    float acc[32];
#pragma unroll
    for (int j = 0; j < 32; ++j) acc[j] = sB[j];
#pragma unroll
    for (int k = 0; k < 16; ++k) {
        float v = in[k];
#pragma unroll
        for (int j = 0; j < 32; ++j) acc[j] += sW[j * 16 + k] * v;
    }
    float4* out = (float4*)(h1 + (size_t)i * 32);
#pragma unroll
    for (int j = 0; j < 8; ++j)
        out[j] = make_float4(fmaxf(acc[4 * j + 0], 0.f), fmaxf(acc[4 * j + 1], 0.f),
                             fmaxf(acc[4 * j + 2], 0.f), fmaxf(acc[4 * j + 3], 0.f));
}

// ------------------------------------------------- gather aggregation via CSR
// PARTS threads per node; each owns 8 floats (2x float4). Edge loop unrolled x2.
template <int WIDTH, int PARTS>
__global__ __launch_bounds__(256) void k_agg(
    const int* __restrict__ row_ptr, const int* __restrict__ sorted_src,
    const float* __restrict__ h, float* __restrict__ agg, int n)
{
    int tid = blockIdx.x * 256 + threadIdx.x;
    int i = tid / PARTS;
    int p = tid % PARTS;
    if (i >= n) return;
    float4 a0 = make_float4(0.f, 0.f, 0.f, 0.f);
    float4 a1 = make_float4(0.f, 0.f, 0.f, 0.f);
    float4 b0 = make_float4(0.f, 0.f, 0.f, 0.f);
    float4 b1 = make_float4(0.f, 0.f, 0.f, 0.f);
    int e0 = row_ptr[i], e1 = row_ptr[i + 1];
    const float* hp = h + p * 8;
    int e = e0;
    for (; e + 2 <= e1; e += 2) {
        int s0 = sorted_src[e];
        int s1 = sorted_src[e + 1];
        const float4* r0 = (const float4*)(hp + (size_t)s0 * WIDTH);
        const float4* r1 = (const float4*)(hp + (size_t)s1 * WIDTH);
        float4 v00 = r0[0], v01 = r0[1];
        float4 v10 = r1[0], v11 = r1[1];
        a0.x += v00.x; a0.y += v00.y; a0.z += v00.z; a0.w += v00.w;
        a1.x += v01.x; a1.y += v01.y; a1.z += v01.z; a1.w += v01.w;
        b0.x += v10.x; b0.y += v10.y; b0.z += v10.z; b0.w += v10.w;
        b1.x += v11.x; b1.y += v11.y; b1.z += v11.z; b1.w += v11.w;
    }
    if (e < e1) {
        int s0 = sorted_src[e];
        const float4* r0 = (const float4*)(hp + (size_t)s0 * WIDTH);
        float4 v00 = r0[0], v01 = r0[1];
        a0.x += v00.x; a0.y += v00.y; a0.z += v00.z; a0.w += v00.w;
        a1.x += v01.x; a1.y += v01.y; a1.z += v01.z; a1.w += v01.w;
    }
    a0.x += b0.x; a0.y += b0.y; a0.z += b0.z; a0.w += b0.w;
    a1.x += b1.x; a1.y += b1.y; a1.z += b1.z; a1.w += b1.w;
    float4* ap = (float4*)(agg + (size_t)i * WIDTH + p * 8);
    ap[0] = a0;
    ap[1] = a1;
}

// ---------------------------------------------------- conv (spill-free layout)
// Block = 256 threads = 4 waves, 64 nodes (lane = node). Wave w computes
// output channels [w*16, w*16+16). acc[16]/thread -> no spills.
template <int WIN>
__global__ __launch_bounds__(256) void k_conv(
    const float* __restrict__ agg, const float* __restrict__ h,
    const float* __restrict__ W_rel, const float* __restrict__ b_rel,
    const float* __restrict__ W_root, float* __restrict__ out, int n)
{
    __shared__ float sWrel[64 * WIN];
    __shared__ float sWroot[64 * WIN];
    __shared__ float sB[64];
    int t = threadIdx.x;
    for (int i = t; i < 64 * WIN; i += 256) {
        sWrel[i] = W_rel[i];
        sWroot[i] = W_root[i];
    }
    if (t < 64) sB[t] = b_rel[t];
    __syncthreads();

    int lane = t & 63;
    int wq = t >> 6;
    int i = blockIdx.x * 64 + lane;
    bool active = (i < n);

    float acc[16];
#pragma unroll
    for (int j = 0; j < 16; ++j) acc[j] = sB[wq * 16 + j];
    const float* wr = sWrel + (size_t)(wq * 16) * WIN;
    const float* wo = sWroot + (size_t)(wq * 16) * WIN;

    if (active) {
        const float4* ap = (const float4*)(agg + (size_t)i * WIN);
        const float4* hp = (const float4*)(h + (size_t)i * WIN);
#pragma unroll
        for (int kc = 0; kc < WIN / 4; ++kc) {
            float4 a4 = ap[kc];
            float4 h4 = hp[kc];
            float av[4] = {a4.x, a4.y, a4.z, a4.w};
            float hv[4] = {h4.x, h4.y, h4.z, h4.w};
#pragma unroll
            for (int q = 0; q < 4; ++q) {
                int k = kc * 4 + q;
#pragma unroll
                for (int j = 0; j < 16; ++j)
                    acc[j] += wr[j * WIN + k] * av[q] + wo[j * WIN + k] * hv[q];
            }
        }
    }
    __syncthreads();  // all reads done before any in-place store
    if (active) {
        float4* op = (float4*)(out + (size_t)i * 64 + wq * 16);
#pragma unroll
        for (int j = 0; j < 4; ++j)
            op[j] = make_float4(fmaxf(acc[4 * j + 0], 0.f), fmaxf(acc[4 * j + 1], 0.f),
                                fmaxf(acc[4 * j + 2], 0.f), fmaxf(acc[4 * j + 3], 0.f));
    }
}

// ------------------------------------------- pool (block per graph) + classifier
__global__ __launch_bounds__(256) void k_pool_cls(
    const float* __restrict__ h3, const int* __restrict__ batch,
    const float* __restrict__ W_cls, const float* __restrict__ b_cls,
    float* __restrict__ out, int n)
{
    __shared__ float part[4][64];
    __shared__ float pool[64];
    __shared__ int range[2];
    int g = blockIdx.x;
    int t = threadIdx.x;

    if (t < 2) {
        int key = g + t;
        int lo = 0, hi = n;
        while (lo < hi) {
            int mid = (lo + hi) >> 1;
            if (batch[mid] < key) lo = mid + 1; else hi = mid;
        }
        range[t] = lo;
    }
    __syncthreads();
    int start = range[0], end = range[1];

    int j = t & 63;
    int sub = t >> 6;
    float local = 0.f;
    for (int i = start + sub; i < end; i += 4) local += h3[(size_t)i * 64 + j];
    part[sub][j] = local;
    __syncthreads();

    if (t < 64) {
        float cnt = (float)(end - start);
        float inv = 1.0f / fmaxf(cnt, 1.0f);
        pool[t] = (part[0][t] + part[1][t] + part[2][t] + part[3][t]) * inv;
    }
    __syncthreads();

    if (t < 10) {
        float acc = b_cls[t];
#pragma unroll
        for (int k = 0; k < 64; ++k) acc += W_cls[t * 64 + k] * pool[k];
        out[(size_t)g * 10 + t] = acc;
    }
}

// ---------------------------------------------------------------- launch
extern "C" void kernel_launch(void* const* d_in, const int* in_sizes, int n_in,
                              void* d_out, int out_size, void* d_ws, size_t ws_size,
                              hipStream_t stream)
{
    const int* x        = (const int*)d_in[0];
    const int* ei       = (const int*)d_in[1];
    const int* batch    = (const int*)d_in[2];
    const float* shape_emb = (const float*)d_in[4];
    const float* color_emb = (const float*)d_in[5];
    const float* W_pre   = (const float*)d_in[6];
    const float* b_pre   = (const float*)d_in[7];
    const float* W_rel1  = (const float*)d_in[8];
    const float* b_rel1  = (const float*)d_in[9];
    const float* W_root1 = (const float*)d_in[10];
    const float* W_rel2  = (const float*)d_in[11];
    const float* b_rel2  = (const float*)d_in[12];
    const float* W_root2 = (const float*)d_in[13];
    const float* W_cls   = (const float*)d_in[14];
    const float* b_cls   = (const float*)d_in[15];

    const int n  = in_sizes[0] / 2;   // 100000
    const int nE = in_sizes[1] / 2;   // 1200000
    const int G  = NGRAPHS;
    const int* src = ei;
    const int* dst = ei + nE;

    // workspace layout:
    //  floats: [0,n*32) h1 | [n*32,n*64) agg1 | [n*64,n*128) h2
    //          agg2/h3 = [0,n*64) (reuses h1+agg1, dead after conv1)
    //  ints at float-offset n*128:
    //    row_ptr[n+1] | hist[n] | cursor[n] | sorted_src[E] | bsum[64] | boffs[64]
    float* ws   = (float*)d_ws;
    float* h1   = ws;
    float* agg1 = ws + (size_t)n * 32;
    float* h2   = ws + (size_t)n * 64;
    float* agg2 = ws;  // also h3 (conv2 writes in-place)
    int* ints       = (int*)(ws + (size_t)n * 128);
    int* row_ptr    = ints;                        // n+1
    int* hist       = ints + (n + 1);              // n
    int* cursor     = ints + (n + 1) + n;          // n
    int* sorted_src = ints + (n + 1) + 2 * n;      // E
    int* bsum       = sorted_src + nE;             // <=64
    int* boffs      = bsum + 64;                   // <=64

    const int EB = (nE + 255) / 256;
    const int NB = (n + 255) / 256;
    const int CB = (n + 63) / 64;
    const int SB = (n + SCAN_CHUNK - 1) / SCAN_CHUNK;  // 25

    // --- CSR build ---
    hipMemsetAsync(hist, 0, (size_t)n * sizeof(int), stream);
    k_hist<<<EB, 256, 0, stream>>>(dst, hist, nE);
    k_scan_part<<<SB, 256, 0, stream>>>(hist, bsum, n);
    k_scan_mid<<<1, 64, 0, stream>>>(bsum, boffs, row_ptr, SB, n);
    k_scan_apply<<<SB, 256, 0, stream>>>(hist, boffs, row_ptr, cursor, n);
    k_scatteridx<<<EB, 256, 0, stream>>>(src, dst, cursor, sorted_src, nE);

    // --- forward ---
    k_pre<<<NB, 256, 0, stream>>>(x, shape_emb, color_emb, W_pre, b_pre, h1, n);
    k_agg<32, 4><<<((size_t)n * 4 + 255) / 256, 256, 0, stream>>>(row_ptr, sorted_src, h1, agg1, n);
    k_conv<32><<<CB, 256, 0, stream>>>(agg1, h1, W_rel1, b_rel1, W_root1, h2, n);
    k_agg<64, 8><<<((size_t)n * 8 + 255) / 256, 256, 0, stream>>>(row_ptr, sorted_src, h2, agg2, n);
    k_conv<64><<<CB, 256, 0, stream>>>(agg2, h2, W_rel2, b_rel2, W_root2, agg2, n);
    k_pool_cls<<<G, 256, 0, stream>>>(agg2, batch, W_cls, b_cls, (float*)d_out, n);
}